// Round 1
// baseline (2130.047 us; speedup 1.0000x reference)
//
#include <hip/hip_runtime.h>
#include <math.h>

// HydraAttention fp32 baseline.
// Pipeline (all on `stream`, sequential):
//   1. Q = qw@x+qb ; K = kw@x+kb ; V = vw@x+vb      (gemm_wb x3)
//   2. per-token L2-normalize Q,K in place          (norm_qk)
//   3. ksum[b,k] = sum_n Kn ; vsum[b,c] = sum_n V   (rowsums)
//   4. denom[b,n] = 1/(4096 + Qn.ksum + eps)        (denom_kernel)
//   5. kv[b,k,c] = sum_n Kn*V  (split-K atomics)    (zero_f32 + gemm_kv)
//   6. wv[b,c,n] = (vsum + kv^T@Qn)*denom           (gemm_wv)
//   7. attn = rw@wv + rb                            (gemm_wb)
//   8. h1 = conv3x3(attn,c1w)+c1b                   (conv3x3 mode 0)
//   9. out = (conv3x3(h1,c2w)+c2b)*x + x            (conv3x3 mode 1)
//
// Buffers: ws = [ Q (32MB) | Kb (32MB) | ksum|vsum|den|kv (~2.3MB) ]
//          V and attn live in d_out (fully overwritten before final store).

#define BM 64
#define BN 64
#define BKT 16

// out[b,m,n] = sum_k W[m,k]*B[b,k,n] + bias[m]   (W row-major [M,K], B [b,K,N])
__global__ __launch_bounds__(256) void gemm_wb(
    const float* __restrict__ W, const float* __restrict__ bias,
    const float* __restrict__ Bm, float* __restrict__ out,
    int M, int N, int K)
{
  __shared__ float As[BKT][BM];
  __shared__ float Bs[BKT][BN];
  int b = blockIdx.z;
  int m0 = blockIdx.y * BM;
  int n0 = blockIdx.x * BN;
  int tid = threadIdx.x;
  int tx = tid & 15, ty = tid >> 4;
  const float* Bb = Bm + (size_t)b * K * N;
  float acc[4][4] = {};
  for (int k0 = 0; k0 < K; k0 += BKT) {
#pragma unroll
    for (int i = 0; i < 4; i++) {
      int e = tid + i * 256;
      int mm = e >> 4, kk = e & 15;
      As[kk][mm] = W[(size_t)(m0 + mm) * K + k0 + kk];
    }
#pragma unroll
    for (int i = 0; i < 4; i++) {
      int e = tid + i * 256;
      int kk = e >> 6, nn = e & 63;
      Bs[kk][nn] = Bb[(size_t)(k0 + kk) * N + n0 + nn];
    }
    __syncthreads();
#pragma unroll
    for (int kk = 0; kk < BKT; kk++) {
      float4 a = *(const float4*)&As[kk][ty * 4];
      float4 bv = *(const float4*)&Bs[kk][tx * 4];
      float av[4] = {a.x, a.y, a.z, a.w};
      float bb[4] = {bv.x, bv.y, bv.z, bv.w};
#pragma unroll
      for (int i = 0; i < 4; i++)
#pragma unroll
        for (int j = 0; j < 4; j++)
          acc[i][j] = fmaf(av[i], bb[j], acc[i][j]);
    }
    __syncthreads();
  }
#pragma unroll
  for (int i = 0; i < 4; i++) {
    int m = m0 + ty * 4 + i;
    float bi = bias[m];
    float4 o;
    o.x = acc[i][0] + bi; o.y = acc[i][1] + bi;
    o.z = acc[i][2] + bi; o.w = acc[i][3] + bi;
    *(float4*)&out[((size_t)b * M + m) * N + n0 + tx * 4] = o;
  }
}

// in-place column L2 normalization of Q and K: [8][256][4096], norm over dim 1
__global__ __launch_bounds__(64) void norm_qk(float* __restrict__ Q, float* __restrict__ K)
{
  int g = blockIdx.x * 64 + threadIdx.x;   // 0..32767 = b*4096+n
  int b = g >> 12;
  int n = g & 4095;
  size_t base = (size_t)b * 256 * 4096 + n;
  float sq = 0.f, sk = 0.f;
  for (int o = 0; o < 256; o++) {
    float q = Q[base + (size_t)o * 4096];
    float k = K[base + (size_t)o * 4096];
    sq = fmaf(q, q, sq);
    sk = fmaf(k, k, sk);
  }
  float rq = 1.0f / sqrtf(sq);
  float rk = 1.0f / sqrtf(sk);
  for (int o = 0; o < 256; o++) {
    size_t idx = base + (size_t)o * 4096;
    Q[idx] *= rq;
    K[idx] *= rk;
  }
}

// ksum[b,o] = sum_n Kn[b,o,n]; vsum[b,o] = sum_n V[b,o,n]
__global__ __launch_bounds__(256) void rowsums(
    const float* __restrict__ Kn, const float* __restrict__ V,
    float* __restrict__ ksum, float* __restrict__ vsum)
{
  int id = blockIdx.x;            // 0..4095
  int which = id >> 11;           // 0 -> ksum, 1 -> vsum
  int rem = id & 2047;
  int b = rem >> 8, o = rem & 255;
  const float* src = which ? V : Kn;
  size_t base = ((size_t)b * 256 + o) * 4096;
  float s = 0.f;
  for (int n = threadIdx.x; n < 4096; n += 256) s += src[base + n];
#pragma unroll
  for (int off = 32; off; off >>= 1) s += __shfl_down(s, off, 64);
  __shared__ float red[4];
  if ((threadIdx.x & 63) == 0) red[threadIdx.x >> 6] = s;
  __syncthreads();
  if (threadIdx.x == 0)
    (which ? vsum : ksum)[b * 256 + o] = red[0] + red[1] + red[2] + red[3];
}

// denom[b,n] = 1/(4096 + sum_k Qn[b,k,n]*ksum[b,k] + eps)
__global__ __launch_bounds__(256) void denom_kernel(
    const float* __restrict__ Qn, const float* __restrict__ ksum,
    float* __restrict__ den)
{
  __shared__ float sk[256];
  int b = blockIdx.x >> 4;                       // 16 blocks per batch
  int n = (blockIdx.x & 15) * 256 + threadIdx.x;
  sk[threadIdx.x] = ksum[b * 256 + threadIdx.x];
  __syncthreads();
  size_t base = (size_t)b * 256 * 4096 + n;
  float acc = 0.f;
  for (int k = 0; k < 256; k++)
    acc = fmaf(Qn[base + (size_t)k * 4096], sk[k], acc);
  den[b * 4096 + n] = 1.0f / (4096.0f + acc + 1e-6f);
}

__global__ __launch_bounds__(256) void zero_f32(float* __restrict__ p, int n)
{
  int i = blockIdx.x * 256 + threadIdx.x;
  if (i < n) p[i] = 0.f;
}

// kv[b,m,c] += sum_{n in split} Kn[b,m,n]*V[b,c,n]   (split-K over n, atomics)
__global__ __launch_bounds__(256) void gemm_kv(
    const float* __restrict__ Kn, const float* __restrict__ V,
    float* __restrict__ kv)
{
  __shared__ float As[BKT][BM];
  __shared__ float Bs[BKT][BN];
  int z = blockIdx.z;
  int b = z >> 3, sp = z & 7;
  int m0 = blockIdx.y * 64, c0 = blockIdx.x * 64;
  int tid = threadIdx.x;
  int tx = tid & 15, ty = tid >> 4;
  const float* Ab = Kn + (size_t)b * 256 * 4096;
  const float* Bb = V + (size_t)b * 256 * 4096;
  float acc[4][4] = {};
  int kend = sp * 512 + 512;
  for (int k0 = sp * 512; k0 < kend; k0 += BKT) {
#pragma unroll
    for (int i = 0; i < 4; i++) {
      int e = tid + i * 256;
      int mm = e >> 4, kk = e & 15;
      As[kk][mm] = Ab[(size_t)(m0 + mm) * 4096 + k0 + kk];
    }
#pragma unroll
    for (int i = 0; i < 4; i++) {
      int e = tid + i * 256;
      int nn = e >> 4, kk = e & 15;
      Bs[kk][nn] = Bb[(size_t)(c0 + nn) * 4096 + k0 + kk];
    }
    __syncthreads();
#pragma unroll
    for (int kk = 0; kk < BKT; kk++) {
      float4 a = *(const float4*)&As[kk][ty * 4];
      float4 bv = *(const float4*)&Bs[kk][tx * 4];
      float av[4] = {a.x, a.y, a.z, a.w};
      float bb[4] = {bv.x, bv.y, bv.z, bv.w};
#pragma unroll
      for (int i = 0; i < 4; i++)
#pragma unroll
        for (int j = 0; j < 4; j++)
          acc[i][j] = fmaf(av[i], bb[j], acc[i][j]);
    }
    __syncthreads();
  }
#pragma unroll
  for (int i = 0; i < 4; i++) {
    int m = m0 + ty * 4 + i;
#pragma unroll
    for (int j = 0; j < 4; j++) {
      int c = c0 + tx * 4 + j;
      atomicAdd(&kv[((size_t)b * 256 + m) * 256 + c], acc[i][j]);
    }
  }
}

// wv[b,m,n] = (vsum[b,m] + sum_k kv[b,k,m]*Qn[b,k,n]) * den[b,n]
__global__ __launch_bounds__(256) void gemm_wv(
    const float* __restrict__ kvm, const float* __restrict__ Qn,
    const float* __restrict__ vsum, const float* __restrict__ den,
    float* __restrict__ wv)
{
  __shared__ float As[BKT][BM];
  __shared__ float Bs[BKT][BN];
  int b = blockIdx.z;
  int m0 = blockIdx.y * BM;
  int n0 = blockIdx.x * BN;
  int tid = threadIdx.x;
  int tx = tid & 15, ty = tid >> 4;
  const float* Ab = kvm + (size_t)b * 256 * 256;
  const float* Bb = Qn + (size_t)b * 256 * 4096;
  float acc[4][4] = {};
  for (int k0 = 0; k0 < 256; k0 += BKT) {
#pragma unroll
    for (int i = 0; i < 4; i++) {
      int e = tid + i * 256;
      int kk = e >> 6, mm = e & 63;
      As[kk][mm] = Ab[(size_t)(k0 + kk) * 256 + m0 + mm];
    }
#pragma unroll
    for (int i = 0; i < 4; i++) {
      int e = tid + i * 256;
      int kk = e >> 6, nn = e & 63;
      Bs[kk][nn] = Bb[(size_t)(k0 + kk) * 4096 + n0 + nn];
    }
    __syncthreads();
#pragma unroll
    for (int kk = 0; kk < BKT; kk++) {
      float4 a = *(const float4*)&As[kk][ty * 4];
      float4 bv = *(const float4*)&Bs[kk][tx * 4];
      float av[4] = {a.x, a.y, a.z, a.w};
      float bb[4] = {bv.x, bv.y, bv.z, bv.w};
#pragma unroll
      for (int i = 0; i < 4; i++)
#pragma unroll
        for (int j = 0; j < 4; j++)
          acc[i][j] = fmaf(av[i], bb[j], acc[i][j]);
    }
    __syncthreads();
  }
#pragma unroll
  for (int i = 0; i < 4; i++) {
    int m = m0 + ty * 4 + i;
    float vs = vsum[b * 256 + m];
    float4 d4 = *(const float4*)&den[b * 4096 + n0 + tx * 4];
    float dv[4] = {d4.x, d4.y, d4.z, d4.w};
    float4 o;
    o.x = (vs + acc[i][0]) * dv[0];
    o.y = (vs + acc[i][1]) * dv[1];
    o.z = (vs + acc[i][2]) * dv[2];
    o.w = (vs + acc[i][3]) * dv[3];
    *(float4*)&wv[((size_t)b * 256 + m) * 4096 + n0 + tx * 4] = o;
  }
}

// 3x3 SAME conv as implicit GEMM over K = 256*9 = 2304.
// mode 0: out = acc + bias.  mode 1: out = (acc+bias)*x + x
__global__ __launch_bounds__(256) void conv3x3(
    const float* __restrict__ in, const float* __restrict__ wgt,
    const float* __restrict__ bias, const float* __restrict__ xres,
    float* __restrict__ out, int mode)
{
  __shared__ float As[BKT][BM];
  __shared__ float Bs[BKT][BN];
  int b = blockIdx.z;
  int m0 = blockIdx.y * BM;
  int n0 = blockIdx.x * BN;
  int tid = threadIdx.x;
  int tx = tid & 15, ty = tid >> 4;
  const float* inb = in + (size_t)b * 256 * 4096;
  float acc[4][4] = {};
  for (int k0 = 0; k0 < 2304; k0 += BKT) {
#pragma unroll
    for (int i = 0; i < 4; i++) {
      int e = tid + i * 256;
      int mm = e >> 4, kk = e & 15;
      As[kk][mm] = wgt[(size_t)(m0 + mm) * 2304 + k0 + kk];
    }
#pragma unroll
    for (int i = 0; i < 4; i++) {
      int e = tid + i * 256;
      int kk = e >> 6, nn = e & 63;
      int k = k0 + kk;
      int c = k / 9;
      int t = k - c * 9;
      int ky = t / 3;
      int dy = ky - 1, dx = (t - ky * 3) - 1;
      int n = n0 + nn;
      int r = (n >> 6) + dy, cl = (n & 63) + dx;
      float v = 0.f;
      if ((unsigned)r < 64u && (unsigned)cl < 64u)
        v = inb[(size_t)c * 4096 + (r << 6) + cl];
      Bs[kk][nn] = v;
    }
    __syncthreads();
#pragma unroll
    for (int kk = 0; kk < BKT; kk++) {
      float4 a = *(const float4*)&As[kk][ty * 4];
      float4 bv = *(const float4*)&Bs[kk][tx * 4];
      float av[4] = {a.x, a.y, a.z, a.w};
      float bb[4] = {bv.x, bv.y, bv.z, bv.w};
#pragma unroll
      for (int i = 0; i < 4; i++)
#pragma unroll
        for (int j = 0; j < 4; j++)
          acc[i][j] = fmaf(av[i], bb[j], acc[i][j]);
    }
    __syncthreads();
  }
#pragma unroll
  for (int i = 0; i < 4; i++) {
    int m = m0 + ty * 4 + i;
    float bi = bias[m];
    size_t rowbase = ((size_t)b * 256 + m) * 4096 + n0 + tx * 4;
    float4 o;
    float h0 = acc[i][0] + bi, h1v = acc[i][1] + bi;
    float h2 = acc[i][2] + bi, h3 = acc[i][3] + bi;
    if (mode) {
      float4 x4 = *(const float4*)&xres[rowbase];
      o.x = fmaf(h0, x4.x, x4.x);
      o.y = fmaf(h1v, x4.y, x4.y);
      o.z = fmaf(h2, x4.z, x4.z);
      o.w = fmaf(h3, x4.w, x4.w);
    } else {
      o.x = h0; o.y = h1v; o.z = h2; o.w = h3;
    }
    *(float4*)&out[rowbase] = o;
  }
}

extern "C" void kernel_launch(void* const* d_in, const int* in_sizes, int n_in,
                              void* d_out, int out_size, void* d_ws, size_t ws_size,
                              hipStream_t stream)
{
  const float* x   = (const float*)d_in[0];
  const float* qw  = (const float*)d_in[1];
  const float* qb  = (const float*)d_in[2];
  const float* kw  = (const float*)d_in[3];
  const float* kb  = (const float*)d_in[4];
  const float* vw  = (const float*)d_in[5];
  const float* vb  = (const float*)d_in[6];
  const float* rw  = (const float*)d_in[7];
  const float* rb  = (const float*)d_in[8];
  const float* c1w = (const float*)d_in[9];
  const float* c1b = (const float*)d_in[10];
  const float* c2w = (const float*)d_in[11];
  const float* c2b = (const float*)d_in[12];
  float* out = (float*)d_out;

  const size_t NELT = 8u * 256u * 4096u;   // 8388608
  float* ws   = (float*)d_ws;
  float* Q    = ws;                // [8][256][4096]
  float* Kb   = Q + NELT;          // [8][256][4096]
  float* ksum = Kb + NELT;         // [8][256]
  float* vsum = ksum + 2048;       // [8][256]
  float* den  = vsum + 2048;       // [8][4096]
  float* kv   = den + 32768;       // [8][256][256]
  float* Vb   = out;               // V lives in d_out until attn
  float* wv   = Kb;                // reuse K buffer
  float* attn = out;               // reuse d_out
  float* h1   = Q;                 // reuse Q buffer

  dim3 blk(256);
  dim3 gproj(64, 4, 8);

  gemm_wb<<<gproj, blk, 0, stream>>>(qw, qb, x, Q, 256, 4096, 256);
  gemm_wb<<<gproj, blk, 0, stream>>>(kw, kb, x, Kb, 256, 4096, 256);
  gemm_wb<<<gproj, blk, 0, stream>>>(vw, vb, x, Vb, 256, 4096, 256);
  norm_qk<<<512, dim3(64), 0, stream>>>(Q, Kb);
  rowsums<<<4096, blk, 0, stream>>>(Kb, Vb, ksum, vsum);
  denom_kernel<<<128, blk, 0, stream>>>(Q, ksum, den);
  zero_f32<<<2048, blk, 0, stream>>>(kv, 8 * 256 * 256);
  gemm_kv<<<dim3(4, 4, 64), blk, 0, stream>>>(Kb, Vb, kv);
  gemm_wv<<<dim3(64, 4, 8), blk, 0, stream>>>(kv, Q, vsum, den, wv);
  gemm_wb<<<gproj, blk, 0, stream>>>(rw, rb, wv, attn, 256, 4096, 256);
  conv3x3<<<dim3(64, 4, 8), blk, 0, stream>>>(attn, c1w, c1b, nullptr, h1, 0);
  conv3x3<<<dim3(64, 4, 8), blk, 0, stream>>>(h1, c2w, c2b, x, out, 1);
}

// Round 2
// 452.157 us; speedup vs baseline: 4.7109x; 4.7109x over previous
//
#include <hip/hip_runtime.h>
#include <math.h>

// HydraAttention — bf16 MFMA version.
// All contractions as D[i][j] = sum_k A[i][k]*B[j][k] (both operands k-contiguous),
// 128x128 tiles, 4 waves (2x2 of 64x64), v_mfma_f32_16x16x32_bf16, 4x4 frags/wave.
//
// Layout plan (bf16 [u16] unless noted):
//   xT16  [b][n][c]   <- transpose+convert of x     (slot0; later wvT16)
//   Qt16  [b][n][ck]  = xT16 @ qw16 + qb, then row-L2-normalized      (slot1)
//   K16   [b][ck][n]  = kw16 @ xT16 + kb, then col-L2-normalized      (slot2; later attnT16)
//   V16   [b][cv][n]  = vw16 @ xT16 + vb                              (slot3; later h1T16)
//   ksum/vsum f32 [b][256];  den f32 [b][4096] (in d_out scratch)
//   kvpart f32 [sp=8][b][cv][ck] (in d_out scratch) -> kvT16 [b][cv][ck]
//   wvT16 [b][n][cv] = (kvT16 @ Qt16 + vsum)*den    (epilogue-transposed store)
//   attnT16 [b][n][co] = wvT16 @ rw16 + rb
//   conv1: h1T16 [b][n][c]  (K reordered (dy,dx,c), halo LDS tile)
//   conv2: out f32 [b][c][n] = (conv+b)*x + x
//
// d_out scratch regions (dead before final conv2 write): kvpart | w16 | wr1 | den

typedef unsigned short u16;
typedef __attribute__((ext_vector_type(8))) short short8;
typedef __attribute__((ext_vector_type(4))) float f32x4;
typedef __attribute__((ext_vector_type(4))) unsigned short us4v;

static __device__ __forceinline__ float b2f(u16 h) {
  unsigned int u = ((unsigned int)h) << 16;
  return __builtin_bit_cast(float, u);
}
static __device__ __forceinline__ u16 f2b(float f) {
  unsigned int u = __builtin_bit_cast(unsigned int, f);
  u += 0x7fffu + ((u >> 16) & 1u);
  return (u16)(u >> 16);
}

#define NB 1048576L   // elements per batch of a [4096][256]-ish big buffer

// ---------------- weight prep: f32->bf16 + conv-weight reorder ----------------
// w16 = [qw|kw|vw|rw] bf16 (4*65536); wr[m][(dy*3+dx)*256+c] = cw[m][c][dy][dx]
__global__ __launch_bounds__(256) void prep_weights(
    const float* __restrict__ qw, const float* __restrict__ kw,
    const float* __restrict__ vw, const float* __restrict__ rw,
    const float* __restrict__ c1w, const float* __restrict__ c2w,
    u16* __restrict__ w16, u16* __restrict__ wr1, u16* __restrict__ wr2)
{
  int g = blockIdx.x * 256 + threadIdx.x;
  if (g < 262144) {
    const float* s = (g < 65536) ? qw : (g < 131072) ? kw : (g < 196608) ? vw : rw;
    w16[g] = f2b(s[g & 65535]);
  } else {
    int g2 = g - 262144;
    int mat = g2 / 589824;
    int e = g2 - mat * 589824;
    int m = e / 2304, rk = e - m * 2304;
    int d = rk >> 8, c = rk & 255;
    float v = (mat ? c2w : c1w)[m * 2304 + c * 9 + d];
    (mat ? wr2 : wr1)[e] = f2b(v);
  }
}

// ---------------- x [b][c][n] f32 -> xT16 [b][n][c] bf16 ----------------
__global__ __launch_bounds__(256) void transposeX(
    const float* __restrict__ x, u16* __restrict__ xT)
{
  __shared__ float T[64][65];
  int n0 = blockIdx.x * 64, c0 = blockIdx.y * 64, b = blockIdx.z;
  int t = threadIdx.x, tn = t & 63, tc = t >> 6;
#pragma unroll
  for (int cc = 0; cc < 16; cc++) {
    int c = tc + cc * 4;
    T[c][tn] = x[(long)b * NB + (long)(c0 + c) * 4096 + n0 + tn];
  }
  __syncthreads();
#pragma unroll
  for (int nn = 0; nn < 16; nn++) {
    int n = tc + nn * 4;
    xT[(long)b * NB + (long)(n0 + n) * 256 + c0 + tn] = f2b(T[tn][n]);
  }
}

// ---------------- generic NT bf16 MFMA GEMM ----------------
// D[i][j] = sum_k A[i][k]*B[j][k].  A: rows of lda, B: rows of ldb.
// mode 0: v = acc + (p1?p1[row]:0) + (p2?p2[col]:0)
// mode 1: v = (acc + p1[b*256+row]) * p2[b*4096+col]
__global__ __launch_bounds__(256) void gemm_nt(
    const u16* __restrict__ A, const u16* __restrict__ B,
    u16* __restrict__ out,
    int K, int lda, int ldb,
    long sAb, long sBb, long sOb, long sR, long sC,
    int mode, const float* __restrict__ p1, const float* __restrict__ p2)
{
  __shared__ __align__(16) u16 As[128 * 40];
  __shared__ __align__(16) u16 Bs[128 * 40];
  int b = blockIdx.z;
  long i0 = (long)blockIdx.y * 128;
  long j0 = (long)blockIdx.x * 128;
  const u16* Ab = A + b * sAb + i0 * lda;
  const u16* Bb = B + b * sBb + j0 * ldb;
  int t = threadIdx.x;
  int wave = t >> 6, lane = t & 63;
  int wi = (wave >> 1) * 64, wj = (wave & 1) * 64;
  int li = lane & 15, quad = lane >> 4;
  f32x4 acc[4][4];
#pragma unroll
  for (int i = 0; i < 4; i++)
#pragma unroll
    for (int j = 0; j < 4; j++) acc[i][j] = (f32x4){0.f, 0.f, 0.f, 0.f};

  for (int k0 = 0; k0 < K; k0 += 32) {
#pragma unroll
    for (int h = 0; h < 2; h++) {
      int id = t + h * 256;
      int r = id >> 2, q = id & 3;
      *(float4*)&As[r * 40 + q * 8] = *(const float4*)&Ab[(long)r * lda + k0 + q * 8];
      *(float4*)&Bs[r * 40 + q * 8] = *(const float4*)&Bb[(long)r * ldb + k0 + q * 8];
    }
    __syncthreads();
    short8 af[4], bf[4];
#pragma unroll
    for (int s = 0; s < 4; s++) af[s] = *(const short8*)&As[(wi + s * 16 + li) * 40 + quad * 8];
#pragma unroll
    for (int s = 0; s < 4; s++) bf[s] = *(const short8*)&Bs[(wj + s * 16 + li) * 40 + quad * 8];
#pragma unroll
    for (int si = 0; si < 4; si++)
#pragma unroll
      for (int sj = 0; sj < 4; sj++)
        acc[si][sj] = __builtin_amdgcn_mfma_f32_16x16x32_bf16(af[si], bf[sj], acc[si][sj], 0, 0, 0);
    __syncthreads();
  }

#pragma unroll
  for (int si = 0; si < 4; si++)
#pragma unroll
    for (int sj = 0; sj < 4; sj++) {
      long col = j0 + wj + sj * 16 + li;
#pragma unroll
      for (int r = 0; r < 4; r++) {
        long row = i0 + wi + si * 16 + quad * 4 + r;
        float v = acc[si][sj][r];
        if (mode == 0) {
          if (p1) v += p1[row];
          if (p2) v += p2[col];
        } else {
          v = (v + p1[b * 256 + row]) * p2[b * 4096 + col];
        }
        out[b * sOb + row * sR + col * sC] = f2b(v);
      }
    }
}

// ---------------- kv split-K GEMM: part[sp][b][cv][ck] f32 ----------------
__global__ __launch_bounds__(256) void gemm_kv(
    const u16* __restrict__ Kn, const u16* __restrict__ V,
    float* __restrict__ part)
{
  __shared__ __align__(16) u16 As[128 * 40];
  __shared__ __align__(16) u16 Bs[128 * 40];
  int z = blockIdx.z;
  int b = z & 7, sp = z >> 3;
  long i0 = (long)blockIdx.y * 128;   // ck
  long j0 = (long)blockIdx.x * 128;   // cv
  const u16* Ab = Kn + (long)b * NB + i0 * 4096;
  const u16* Bb = V + (long)b * NB + j0 * 4096;
  int t = threadIdx.x;
  int wave = t >> 6, lane = t & 63;
  int wi = (wave >> 1) * 64, wj = (wave & 1) * 64;
  int li = lane & 15, quad = lane >> 4;
  f32x4 acc[4][4];
#pragma unroll
  for (int i = 0; i < 4; i++)
#pragma unroll
    for (int j = 0; j < 4; j++) acc[i][j] = (f32x4){0.f, 0.f, 0.f, 0.f};

  int kend = sp * 512 + 512;
  for (int k0 = sp * 512; k0 < kend; k0 += 32) {
#pragma unroll
    for (int h = 0; h < 2; h++) {
      int id = t + h * 256;
      int r = id >> 2, q = id & 3;
      *(float4*)&As[r * 40 + q * 8] = *(const float4*)&Ab[(long)r * 4096 + k0 + q * 8];
      *(float4*)&Bs[r * 40 + q * 8] = *(const float4*)&Bb[(long)r * 4096 + k0 + q * 8];
    }
    __syncthreads();
    short8 af[4], bf[4];
#pragma unroll
    for (int s = 0; s < 4; s++) af[s] = *(const short8*)&As[(wi + s * 16 + li) * 40 + quad * 8];
#pragma unroll
    for (int s = 0; s < 4; s++) bf[s] = *(const short8*)&Bs[(wj + s * 16 + li) * 40 + quad * 8];
#pragma unroll
    for (int si = 0; si < 4; si++)
#pragma unroll
      for (int sj = 0; sj < 4; sj++)
        acc[si][sj] = __builtin_amdgcn_mfma_f32_16x16x32_bf16(af[si], bf[sj], acc[si][sj], 0, 0, 0);
    __syncthreads();
  }

  float* outp = part + ((long)sp * 8 + b) * 65536;
#pragma unroll
  for (int si = 0; si < 4; si++)
#pragma unroll
    for (int sj = 0; sj < 4; sj++) {
      long col = j0 + wj + sj * 16 + li;   // cv
#pragma unroll
      for (int r = 0; r < 4; r++) {
        long row = i0 + wi + si * 16 + quad * 4 + r;  // ck
        outp[col * 256 + row] = acc[si][sj][r];
      }
    }
}

// kvT16[b][cv][ck] = bf16( sum_sp part[sp][b][cv][ck] )
__global__ __launch_bounds__(256) void reduce_kv(
    const float* __restrict__ part, u16* __restrict__ kvT)
{
  int g = blockIdx.x * 256 + threadIdx.x;  // 524288
  float s = 0.f;
#pragma unroll
  for (int sp = 0; sp < 8; sp++) s += part[(long)sp * 524288 + g];
  kvT[g] = f2b(s);
}

// ---------------- normalize Qt rows (256 contiguous) ----------------
__global__ __launch_bounds__(256) void normQ(u16* __restrict__ Qt)
{
  int row = blockIdx.x * 4 + (threadIdx.x >> 6);
  int lane = threadIdx.x & 63;
  u16* p = Qt + (long)row * 256 + lane * 4;
  us4v v = *(const us4v*)p;
  float f0 = b2f(v[0]), f1 = b2f(v[1]), f2 = b2f(v[2]), f3 = b2f(v[3]);
  float s = f0 * f0 + f1 * f1 + f2 * f2 + f3 * f3;
#pragma unroll
  for (int m = 32; m; m >>= 1) s += __shfl_xor(s, m, 64);
  float r = 1.0f / sqrtf(s);
  us4v o;
  o[0] = f2b(f0 * r); o[1] = f2b(f1 * r); o[2] = f2b(f2 * r); o[3] = f2b(f3 * r);
  *(us4v*)p = o;
}

// ---------------- normalize K columns (stride 4096) in place ----------------
__global__ __launch_bounds__(256) void normK(u16* __restrict__ K16)
{
  int g = blockIdx.x * 256 + threadIdx.x;  // 32768 = b*4096+n
  int b = g >> 12, n = g & 4095;
  u16* base = K16 + (long)b * NB + n;
  float s = 0.f;
  for (int o = 0; o < 256; o++) {
    float v = b2f(base[(long)o * 4096]);
    s = fmaf(v, v, s);
  }
  float r = 1.0f / sqrtf(s);
  for (int o = 0; o < 256; o++) {
    long a = (long)o * 4096;
    base[a] = f2b(b2f(base[a]) * r);
  }
}

// ---------------- ksum (from Kn16) and vsum (from V16) ----------------
__global__ __launch_bounds__(256) void rowsums16(
    const u16* __restrict__ Kn, const u16* __restrict__ V,
    float* __restrict__ ksum, float* __restrict__ vsum)
{
  int id = blockIdx.x;           // 0..4095
  int which = id >> 11;
  int rem = id & 2047;
  int b = rem >> 8, o = rem & 255;
  const u16* src = (which ? V : Kn) + (long)b * NB + (long)o * 4096;
  float s = 0.f;
  for (int n = threadIdx.x; n < 4096; n += 256) s += b2f(src[n]);
#pragma unroll
  for (int off = 32; off; off >>= 1) s += __shfl_down(s, off, 64);
  __shared__ float red[4];
  if ((threadIdx.x & 63) == 0) red[threadIdx.x >> 6] = s;
  __syncthreads();
  if (threadIdx.x == 0)
    (which ? vsum : ksum)[b * 256 + o] = red[0] + red[1] + red[2] + red[3];
}

// ---------------- den[b][n] = 1/(4096 + Qn[n,:].ksum[b,:] + eps) ----------------
__global__ __launch_bounds__(256) void denom_k(
    const u16* __restrict__ Qt, const float* __restrict__ ksum,
    float* __restrict__ den)
{
  int row = blockIdx.x * 4 + (threadIdx.x >> 6);
  int lane = threadIdx.x & 63;
  int b = row >> 12;
  us4v v = *(const us4v*)(Qt + (long)row * 256 + lane * 4);
  float4 ks = *(const float4*)&ksum[b * 256 + lane * 4];
  float s = b2f(v[0]) * ks.x + b2f(v[1]) * ks.y + b2f(v[2]) * ks.z + b2f(v[3]) * ks.w;
#pragma unroll
  for (int m = 32; m; m >>= 1) s += __shfl_xor(s, m, 64);
  if (lane == 0) den[row] = 1.0f / (4096.0f + s + 1e-6f);
}

// ---------------- 3x3 conv, implicit GEMM, bf16 MFMA ----------------
// inT [b][n][256]; wr [256][(dy*3+dx)*256+c].
// mode 0: out16[b][n][256] = acc + bias[m]   (transposed store)
// mode 1: out32[b][m][4096] = (acc+bias[m])*x + x
__global__ __launch_bounds__(256) void conv3x3_mfma(
    const u16* __restrict__ inT, const u16* __restrict__ wr,
    const float* __restrict__ bias, const float* __restrict__ xres,
    u16* __restrict__ out16, float* __restrict__ out32, int mode)
{
  __shared__ __align__(16) u16 Hs[4 * 66 * 40];   // halo: rows r0-1..r0+2, cols -1..64, 32 ch
  __shared__ __align__(16) u16 As[128 * 40];
  int b = blockIdx.z;
  int m0 = blockIdx.y * 128;
  int n0 = blockIdx.x * 128;
  int r0 = n0 >> 6;                                // tile covers image rows r0, r0+1
  int t = threadIdx.x;
  int wave = t >> 6, lane = t & 63;
  int wi = (wave >> 1) * 64, wj = (wave & 1) * 64;
  int li = lane & 15, quad = lane >> 4;
  const u16* inb = inT + (long)b * NB;
  f32x4 acc[4][4];
#pragma unroll
  for (int i = 0; i < 4; i++)
#pragma unroll
    for (int j = 0; j < 4; j++) acc[i][j] = (f32x4){0.f, 0.f, 0.f, 0.f};

#pragma unroll 1
  for (int c0 = 0; c0 < 256; c0 += 32) {
    // stage halo tile: 4 rows x 66 cols x 32 channels
    for (int p = t; p < 264; p += 256) {
      int rr = p / 66, xx = p - rr * 66;
      int ri = r0 + rr - 1, xi = xx - 1;
      u16* dst = &Hs[(rr * 66 + xx) * 40];
      if ((unsigned)ri < 64u && (unsigned)xi < 64u) {
        const u16* src = inb + (long)(ri * 64 + xi) * 256 + c0;
#pragma unroll
        for (int q = 0; q < 4; q++) *(float4*)&dst[q * 8] = *(const float4*)&src[q * 8];
      } else {
        float4 z = {0.f, 0.f, 0.f, 0.f};
#pragma unroll
        for (int q = 0; q < 4; q++) *(float4*)&dst[q * 8] = z;
      }
    }
#pragma unroll 1
    for (int d = 0; d < 9; d++) {
      int kbase = d * 256 + c0;
#pragma unroll
      for (int h = 0; h < 2; h++) {
        int id = t + h * 256;
        int r = id >> 2, q = id & 3;
        *(float4*)&As[r * 40 + q * 8] = *(const float4*)&wr[(long)(m0 + r) * 2304 + kbase + q * 8];
      }
      __syncthreads();   // Hs (first d) + As visible
      short8 af[4], bf[4];
#pragma unroll
      for (int s = 0; s < 4; s++) af[s] = *(const short8*)&As[(wi + s * 16 + li) * 40 + quad * 8];
      int dy = d / 3, dx = d - dy * 3;
#pragma unroll
      for (int s = 0; s < 4; s++) {
        int pl = wj + s * 16 + li;
        int rh = (pl >> 6) + dy;
        int ch = (pl & 63) + dx;
        bf[s] = *(const short8*)&Hs[(rh * 66 + ch) * 40 + quad * 8];
      }
#pragma unroll
      for (int si = 0; si < 4; si++)
#pragma unroll
        for (int sj = 0; sj < 4; sj++)
          acc[si][sj] = __builtin_amdgcn_mfma_f32_16x16x32_bf16(af[si], bf[sj], acc[si][sj], 0, 0, 0);
      __syncthreads();   // done with As (and Hs on last d) before restage
    }
  }

#pragma unroll
  for (int si = 0; si < 4; si++)
#pragma unroll
    for (int sj = 0; sj < 4; sj++) {
      int n = n0 + wj + sj * 16 + li;
#pragma unroll
      for (int r = 0; r < 4; r++) {
        int m = m0 + wi + si * 16 + quad * 4 + r;
        float v = acc[si][sj][r] + bias[m];
        if (mode == 0) {
          out16[(long)b * NB + (long)n * 256 + m] = f2b(v);
        } else {
          long a = (long)b * NB + (long)m * 4096 + n;
          float xv = xres[a];
          out32[a] = fmaf(v, xv, xv);
        }
      }
    }
}

// ---------------- host ----------------
extern "C" void kernel_launch(void* const* d_in, const int* in_sizes, int n_in,
                              void* d_out, int out_size, void* d_ws, size_t ws_size,
                              hipStream_t stream)
{
  const float* x   = (const float*)d_in[0];
  const float* qw  = (const float*)d_in[1];
  const float* qb  = (const float*)d_in[2];
  const float* kw  = (const float*)d_in[3];
  const float* kb  = (const float*)d_in[4];
  const float* vw  = (const float*)d_in[5];
  const float* vb  = (const float*)d_in[6];
  const float* rw  = (const float*)d_in[7];
  const float* rb  = (const float*)d_in[8];
  const float* c1w = (const float*)d_in[9];
  const float* c1b = (const float*)d_in[10];
  const float* c2w = (const float*)d_in[11];
  const float* c2b = (const float*)d_in[12];

  // ws layout (bf16 slots of 16.8MB each)
  u16* U     = (u16*)d_ws;
  u16* xT16  = U;                    // slot0; later wvT16
  u16* Qt16  = U + 8388608;          // slot1
  u16* K16   = U + 16777216;         // slot2; later attnT16
  u16* V16   = U + 25165824;         // slot3; later h1T16
  u16* wr2   = U + 33554432;         // 589824 u16
  u16* kvT16 = U + 34144256;         // 524288 u16
  float* Fws = (float*)(U + 34668544);
  float* ksum = Fws;                 // 2048
  float* vsum = Fws + 2048;          // 2048

  // d_out scratch (all dead before final conv2 writes d_out)
  float* outF   = (float*)d_out;
  float* kvpart = outF;                                   // 16,777,216 B
  u16*   w16    = (u16*)((char*)d_out + 16777216);        // 524,288 B
  u16*   wr1    = (u16*)((char*)d_out + 17301504);        // 1,179,648 B
  float* den    = (float*)((char*)d_out + 18481152);      // 131,072 B
  u16* qw16 = w16, *kw16 = w16 + 65536, *vw16 = w16 + 131072, *rw16 = w16 + 196608;

  u16* wvT16   = xT16;
  u16* attnT16 = K16;
  u16* h1T16   = V16;

  dim3 blk(256);

  prep_weights<<<5632, blk, 0, stream>>>(qw, kw, vw, rw, c1w, c2w, w16, wr1, wr2);
  transposeX<<<dim3(64, 4, 8), blk, 0, stream>>>(x, xT16);

  // Qt[b][n][ck] = xT @ qw^T + qb
  gemm_nt<<<dim3(2, 32, 8), blk, 0, stream>>>(xT16, qw16, Qt16,
      256, 256, 256, NB, 0L, NB, 256L, 1L, 0, nullptr, qb);
  // K[b][ck][n] = kw @ x + kb
  gemm_nt<<<dim3(32, 2, 8), blk, 0, stream>>>(kw16, xT16, K16,
      256, 256, 256, 0L, NB, NB, 4096L, 1L, 0, kb, nullptr);
  // V[b][cv][n] = vw @ x + vb
  gemm_nt<<<dim3(32, 2, 8), blk, 0, stream>>>(vw16, xT16, V16,
      256, 256, 256, 0L, NB, NB, 4096L, 1L, 0, vb, nullptr);

  normQ<<<8192, blk, 0, stream>>>(Qt16);
  normK<<<128, blk, 0, stream>>>(K16);
  rowsums16<<<4096, blk, 0, stream>>>(K16, V16, ksum, vsum);
  denom_k<<<8192, blk, 0, stream>>>(Qt16, ksum, den);

  gemm_kv<<<dim3(2, 2, 64), blk, 0, stream>>>(K16, V16, kvpart);
  reduce_kv<<<2048, blk, 0, stream>>>(kvpart, kvT16);

  // wvT[b][n][cv] = (kvT @ Qn^T + vsum) * den
  gemm_nt<<<dim3(32, 2, 8), blk, 0, stream>>>(kvT16, Qt16, wvT16,
      256, 256, 256, 65536L, NB, NB, 1L, 256L, 1, vsum, den);
  // attnT[b][n][co] = wvT @ rw^T + rb
  gemm_nt<<<dim3(2, 32, 8), blk, 0, stream>>>(wvT16, rw16, attnT16,
      256, 256, 256, NB, 0L, NB, 256L, 1L, 0, nullptr, rb);

  conv3x3_mfma<<<dim3(32, 2, 8), blk, 0, stream>>>(attnT16, wr1, c1b, nullptr, h1T16, nullptr, 0);
  conv3x3_mfma<<<dim3(32, 2, 8), blk, 0, stream>>>(h1T16, wr2, c2b, x, nullptr, outF, 1);
}

// Round 4
// 435.791 us; speedup vs baseline: 4.8878x; 1.0376x over previous
//
#include <hip/hip_runtime.h>
#include <math.h>

// HydraAttention R4 — R3 design + fix: zpad removed (was in d_out, raced with
// conv2's output writes). OOB halo chunks are now zeroed via direct LDS stores.
//
// Pipeline:
//   prep1: f32->bf16 weights (qw | stacked kw/vw | rw^T | conv reorders), kvbias
//   prep_T: T[m][t] = sum_co c1w[m][co][t]*rb[co]
//   corr_k: corr[m][p] = c1b[m] + sum_{taps valid at p} T[m][t]   (exact rb border term)
//   transposeX: x [b][c][n] f32 -> xT16 [b][n][c] bf16
//   gemm_nt w1' = wr1 @ rwT   (folds rw into conv1 weights, [m][t*256+cv])
//   gemm_nt Qt  [b][n][ck] = xT @ qw^T + qb
//   gemm_nt KV  [b][512][n] = [kw|vw] @ x + [kb|vb]
//   normQ, sumsqK + scale_sums, denom_k
//   gemm_kv (split-n=8, f32 partials) + reduce_kv -> kvT16 [b][cv][ck]
//   gemm_nt wv [b][n][cv] = (Qt @ kv + vsum)*den
//   conv3x3 mode0: h1T [b][n][c] = conv(wvT, w1') + corr
//   conv3x3 mode1: out f32 [b][c][n] = (conv(h1T, wr2)+c2b)*x + x
//
// Conv: m-tile 64, n-tile 256 (4 image rows + halo), all-9-tap weight stage,
// 2 barriers per 32-ch chunk. Staging via global_load_lds width=16 into
// UNPADDED LDS (64B strides -> 2-way bank alias, free per m136).

typedef unsigned short u16;
typedef __attribute__((ext_vector_type(8))) short short8;
typedef __attribute__((ext_vector_type(4))) float f32x4;
typedef __attribute__((ext_vector_type(4))) unsigned short us4v;

#define ASYNC16(g, l) __builtin_amdgcn_global_load_lds( \
    (const __attribute__((address_space(1))) unsigned int*)(g), \
    (__attribute__((address_space(3))) unsigned int*)(l), 16, 0, 0)

static __device__ __forceinline__ float b2f(u16 h) {
  unsigned int u = ((unsigned int)h) << 16;
  return __builtin_bit_cast(float, u);
}
static __device__ __forceinline__ u16 f2b(float f) {
  unsigned int u = __builtin_bit_cast(unsigned int, f);
  u += 0x7fffu + ((u >> 16) & 1u);
  return (u16)(u >> 16);
}

#define NB 1048576L

// ---------------- prep1: weight converts/reorders + kvbias ----------------
__global__ __launch_bounds__(256) void prep1(
    const float* __restrict__ qw, const float* __restrict__ kw,
    const float* __restrict__ vw, const float* __restrict__ rw,
    const float* __restrict__ c1w, const float* __restrict__ c2w,
    const float* __restrict__ kb, const float* __restrict__ vb,
    u16* __restrict__ qw16, u16* __restrict__ kvw16, u16* __restrict__ rwT16,
    u16* __restrict__ wr1, u16* __restrict__ wr2,
    float* __restrict__ kvbias)
{
  if (blockIdx.x == 5632) {
    int t = threadIdx.x;
    if (t < 512) kvbias[t] = (t < 256) ? kb[t] : vb[t - 256];
    return;
  }
  long g = (long)blockIdx.x * 256 + threadIdx.x;
  if (g < 65536) {
    qw16[g] = f2b(qw[g]);
  } else if (g < 196608) {
    long e = g - 65536;
    kvw16[e] = f2b(e < 65536 ? kw[e] : vw[e - 65536]);
  } else if (g < 262144) {
    long e = g - 196608;
    int cv = e >> 8, co = e & 255;
    rwT16[e] = f2b(rw[co * 256 + cv]);
  } else if (g < 851968) {
    long e = g - 262144;
    int m = e / 2304, r = e - m * 2304;
    int d = r >> 8, c = r & 255;
    wr1[e] = f2b(c1w[m * 2304 + c * 9 + d]);
  } else {
    long e = g - 851968;
    int m = e / 2304, r = e - m * 2304;
    int d = r >> 8, c = r & 255;
    wr2[e] = f2b(c2w[m * 2304 + c * 9 + d]);
  }
}

// T[m*9+t] = sum_co c1w[m][co][t]*rb[co]
__global__ __launch_bounds__(256) void prep_T(
    const float* __restrict__ c1w, const float* __restrict__ rb, float* __restrict__ T)
{
  int e = blockIdx.x * 256 + threadIdx.x;   // 2304
  int m = e / 9, d = e - m * 9;
  float s = 0.f;
  for (int co = 0; co < 256; co++) s += c1w[m * 2304 + co * 9 + d] * rb[co];
  T[e] = s;
}

// corr[m][p] = c1b[m] + sum_{t valid at p} T[m][t]
__global__ __launch_bounds__(256) void corr_k(
    const float* __restrict__ T, const float* __restrict__ c1b, float* __restrict__ corr)
{
  int e = blockIdx.x * 256 + threadIdx.x;   // 1048576
  int m = e >> 12, p = e & 4095;
  int y = p >> 6, xx = p & 63;
  float s = c1b[m];
#pragma unroll
  for (int d = 0; d < 9; d++) {
    int dy = d / 3 - 1, dx = d - (d / 3) * 3 - 1;
    if ((unsigned)(y + dy) < 64u && (unsigned)(xx + dx) < 64u) s += T[m * 9 + d];
  }
  corr[e] = s;
}

// ---------------- x [b][c][n] f32 -> xT16 [b][n][c] bf16 ----------------
__global__ __launch_bounds__(256) void transposeX(
    const float* __restrict__ x, u16* __restrict__ xT)
{
  __shared__ float T[64][65];
  int n0 = blockIdx.x * 64, c0 = blockIdx.y * 64, b = blockIdx.z;
  int t = threadIdx.x;
#pragma unroll
  for (int i = 0; i < 4; i++) {
    int c = (t >> 4) + i * 16, nn = (t & 15) * 4;
    float4 v = *(const float4*)&x[(long)b * NB + (long)(c0 + c) * 4096 + n0 + nn];
    T[c][nn] = v.x; T[c][nn + 1] = v.y; T[c][nn + 2] = v.z; T[c][nn + 3] = v.w;
  }
  __syncthreads();
#pragma unroll
  for (int i = 0; i < 4; i++) {
    int n = (t >> 4) + i * 16, cc = (t & 15) * 4;
    us4v o;
#pragma unroll
    for (int e = 0; e < 4; e++) o[e] = f2b(T[cc + e][n]);
    *(us4v*)&xT[(long)b * NB + (long)(n0 + n) * 256 + c0 + cc] = o;
  }
}

// ---------------- generic NT bf16 MFMA GEMM (global_load_lds staging) ----------------
// D[i][j] = sum_k A[i][k]*B[j][k]
// mode 0: v += (p1?p1[row]:0) + (p2?p2[col]:0)
// mode 2: v = (v + p1[b*256+col]) * p2[b*4096+row]
__global__ __launch_bounds__(256) void gemm_nt(
    const u16* __restrict__ A, const u16* __restrict__ B, u16* __restrict__ out,
    int K, int lda, int ldb, long sAb, long sBb, long sOb, long sR, long sC,
    int mode, const float* __restrict__ p1, const float* __restrict__ p2)
{
  __shared__ __align__(16) u16 As[128 * 32];
  __shared__ __align__(16) u16 Bs[128 * 32];
  int b = blockIdx.z;
  long i0 = (long)blockIdx.y * 128;
  long j0 = (long)blockIdx.x * 128;
  const u16* Ab = A + b * sAb + i0 * lda;
  const u16* Bb = B + b * sBb + j0 * ldb;
  int t = threadIdx.x, wave = t >> 6, lane = t & 63;
  int wi = (wave >> 1) * 64, wj = (wave & 1) * 64;
  int li = lane & 15, quad = lane >> 4;
  f32x4 acc[4][4];
#pragma unroll
  for (int i = 0; i < 4; i++)
#pragma unroll
    for (int j = 0; j < 4; j++) acc[i][j] = (f32x4){0.f, 0.f, 0.f, 0.f};

  for (int k0 = 0; k0 < K; k0 += 32) {
#pragma unroll
    for (int h = 0; h < 2; h++) {
      int chunk = wave * 128 + h * 64 + lane;
      int r = chunk >> 2, q = chunk & 3;
      ASYNC16(Ab + (long)r * lda + k0 + q * 8, &As[(wave * 128 + h * 64) * 8]);
      ASYNC16(Bb + (long)r * ldb + k0 + q * 8, &Bs[(wave * 128 + h * 64) * 8]);
    }
    __syncthreads();
    short8 af[4], bf[4];
#pragma unroll
    for (int s = 0; s < 4; s++) af[s] = *(const short8*)&As[(wi + s * 16 + li) * 32 + quad * 8];
#pragma unroll
    for (int s = 0; s < 4; s++) bf[s] = *(const short8*)&Bs[(wj + s * 16 + li) * 32 + quad * 8];
#pragma unroll
    for (int si = 0; si < 4; si++)
#pragma unroll
      for (int sj = 0; sj < 4; sj++)
        acc[si][sj] = __builtin_amdgcn_mfma_f32_16x16x32_bf16(af[si], bf[sj], acc[si][sj], 0, 0, 0);
    __syncthreads();
  }

#pragma unroll
  for (int si = 0; si < 4; si++)
#pragma unroll
    for (int sj = 0; sj < 4; sj++) {
      long col = j0 + wj + sj * 16 + li;
#pragma unroll
      for (int r = 0; r < 4; r++) {
        long row = i0 + wi + si * 16 + quad * 4 + r;
        float v = acc[si][sj][r];
        if (mode == 0) {
          if (p1) v += p1[row];
          if (p2) v += p2[col];
        } else {
          v = (v + p1[b * 256 + col]) * p2[b * 4096 + row];
        }
        out[b * sOb + row * sR + col * sC] = f2b(v);
      }
    }
}

// ---------------- kv split-n GEMM: part[sp][b][cv][ck] f32 ----------------
__global__ __launch_bounds__(256) void gemm_kv(
    const u16* __restrict__ KV, float* __restrict__ part)
{
  __shared__ __align__(16) u16 As[128 * 32];
  __shared__ __align__(16) u16 Bs[128 * 32];
  int z = blockIdx.z;
  int b = z & 7, sp = z >> 3;
  long i0 = (long)blockIdx.y * 128;   // ck
  long j0 = (long)blockIdx.x * 128;   // cv
  const u16* Ab = KV + (long)b * 2 * NB + i0 * 4096;        // K rows
  const u16* Bb = KV + (long)b * 2 * NB + NB + j0 * 4096;   // V rows
  int t = threadIdx.x, wave = t >> 6, lane = t & 63;
  int wi = (wave >> 1) * 64, wj = (wave & 1) * 64;
  int li = lane & 15, quad = lane >> 4;
  f32x4 acc[4][4];
#pragma unroll
  for (int i = 0; i < 4; i++)
#pragma unroll
    for (int j = 0; j < 4; j++) acc[i][j] = (f32x4){0.f, 0.f, 0.f, 0.f};

  int kend = sp * 512 + 512;
  for (int k0 = sp * 512; k0 < kend; k0 += 32) {
#pragma unroll
    for (int h = 0; h < 2; h++) {
      int chunk = wave * 128 + h * 64 + lane;
      int r = chunk >> 2, q = chunk & 3;
      ASYNC16(Ab + (long)r * 4096 + k0 + q * 8, &As[(wave * 128 + h * 64) * 8]);
      ASYNC16(Bb + (long)r * 4096 + k0 + q * 8, &Bs[(wave * 128 + h * 64) * 8]);
    }
    __syncthreads();
    short8 af[4], bf[4];
#pragma unroll
    for (int s = 0; s < 4; s++) af[s] = *(const short8*)&As[(wi + s * 16 + li) * 32 + quad * 8];
#pragma unroll
    for (int s = 0; s < 4; s++) bf[s] = *(const short8*)&Bs[(wj + s * 16 + li) * 32 + quad * 8];
#pragma unroll
    for (int si = 0; si < 4; si++)
#pragma unroll
      for (int sj = 0; sj < 4; sj++)
        acc[si][sj] = __builtin_amdgcn_mfma_f32_16x16x32_bf16(af[si], bf[sj], acc[si][sj], 0, 0, 0);
    __syncthreads();
  }

  float* outp = part + ((long)sp * 8 + b) * 65536;
#pragma unroll
  for (int si = 0; si < 4; si++)
#pragma unroll
    for (int sj = 0; sj < 4; sj++) {
      long col = j0 + wj + sj * 16 + li;   // cv
#pragma unroll
      for (int r = 0; r < 4; r++) {
        long row = i0 + wi + si * 16 + quad * 4 + r;  // ck
        outp[col * 256 + row] = acc[si][sj][r];
      }
    }
}

__global__ __launch_bounds__(256) void reduce_kv(
    const float* __restrict__ part, u16* __restrict__ kvT)
{
  int g = blockIdx.x * 256 + threadIdx.x;  // 524288
  float s = 0.f;
#pragma unroll
  for (int sp = 0; sp < 8; sp++) s += part[(long)sp * 524288 + g];
  kvT[g] = f2b(s);
}

// ---------------- normalize Qt rows ----------------
__global__ __launch_bounds__(256) void normQ(u16* __restrict__ Qt)
{
  int row = blockIdx.x * 4 + (threadIdx.x >> 6);
  int lane = threadIdx.x & 63;
  u16* p = Qt + (long)row * 256 + lane * 4;
  us4v v = *(const us4v*)p;
  float f0 = b2f(v[0]), f1 = b2f(v[1]), f2 = b2f(v[2]), f3 = b2f(v[3]);
  float s = f0 * f0 + f1 * f1 + f2 * f2 + f3 * f3;
#pragma unroll
  for (int m = 32; m; m >>= 1) s += __shfl_xor(s, m, 64);
  float r = 1.0f / sqrtf(s);
  us4v o;
  o[0] = f2b(f0 * r); o[1] = f2b(f1 * r); o[2] = f2b(f2 * r); o[3] = f2b(f3 * r);
  *(us4v*)p = o;
}

// ---------------- K column sumsq -> rsqK[b][n] ----------------
__global__ __launch_bounds__(256) void sumsqK(
    const u16* __restrict__ KV, float* __restrict__ rsqK)
{
  __shared__ float red[8][132];
  int b = blockIdx.x >> 5, nc = blockIdx.x & 31;
  int n0 = nc * 128;
  int t = threadIdx.x;
  int nn = (t & 31) * 4, cg = t >> 5;
  const u16* base = KV + (long)b * 2 * NB;
  float s0 = 0.f, s1 = 0.f, s2 = 0.f, s3 = 0.f;
  for (int st = 0; st < 32; st++) {
    int c = cg + st * 8;
    us4v v = *(const us4v*)(base + (long)c * 4096 + n0 + nn);
    float a = b2f(v[0]), bb = b2f(v[1]), cc = b2f(v[2]), dd = b2f(v[3]);
    s0 = fmaf(a, a, s0); s1 = fmaf(bb, bb, s1);
    s2 = fmaf(cc, cc, s2); s3 = fmaf(dd, dd, s3);
  }
  red[cg][nn] = s0; red[cg][nn + 1] = s1; red[cg][nn + 2] = s2; red[cg][nn + 3] = s3;
  __syncthreads();
  if (t < 128) {
    float s = 0.f;
#pragma unroll
    for (int g = 0; g < 8; g++) s += red[g][t];
    rsqK[b * 4096 + n0 + t] = 1.0f / sqrtf(s);
  }
}

// ---------------- scale K rows by rsqK + ksum; V rows -> vsum ----------------
__global__ __launch_bounds__(256) void scale_sums(
    u16* __restrict__ KV, const float* __restrict__ rsqK,
    float* __restrict__ ksum, float* __restrict__ vsum)
{
  int z = blockIdx.x;
  int isV = z >> 11, rem = z & 2047, b = rem >> 8, c = rem & 255;
  u16* row = KV + (long)b * 2 * NB + (long)isV * NB + (long)c * 4096;
  const float* rq = rsqK + b * 4096;
  int t = threadIdx.x;
  float s = 0.f;
  short8 v0 = *(const short8*)&row[t * 16];
  short8 v1 = *(const short8*)&row[t * 16 + 8];
  if (!isV) {
    short8 o0, o1;
#pragma unroll
    for (int e = 0; e < 8; e++) {
      float a = b2f((u16)v0[e]) * rq[t * 16 + e];
      float bb = b2f((u16)v1[e]) * rq[t * 16 + 8 + e];
      s += a + bb;
      o0[e] = (short)f2b(a); o1[e] = (short)f2b(bb);
    }
    *(short8*)&row[t * 16] = o0;
    *(short8*)&row[t * 16 + 8] = o1;
  } else {
#pragma unroll
    for (int e = 0; e < 8; e++) s += b2f((u16)v0[e]) + b2f((u16)v1[e]);
  }
#pragma unroll
  for (int off = 32; off; off >>= 1) s += __shfl_down(s, off, 64);
  __shared__ float red[4];
  if ((t & 63) == 0) red[t >> 6] = s;
  __syncthreads();
  if (t == 0)
    (isV ? vsum : ksum)[b * 256 + c] = red[0] + red[1] + red[2] + red[3];
}

// ---------------- den[b][n] = 1/(4096 + Qn[n,:].ksum + eps) ----------------
__global__ __launch_bounds__(256) void denom_k(
    const u16* __restrict__ Qt, const float* __restrict__ ksum,
    float* __restrict__ den)
{
  int row = blockIdx.x * 4 + (threadIdx.x >> 6);
  int lane = threadIdx.x & 63;
  int b = row >> 12;
  us4v v = *(const us4v*)(Qt + (long)row * 256 + lane * 4);
  float4 ks = *(const float4*)&ksum[b * 256 + lane * 4];
  float s = b2f(v[0]) * ks.x + b2f(v[1]) * ks.y + b2f(v[2]) * ks.z + b2f(v[3]) * ks.w;
#pragma unroll
  for (int m = 32; m; m >>= 1) s += __shfl_xor(s, m, 64);
  if (lane == 0) den[row] = 1.0f / (4096.0f + s + 1e-6f);
}

// ---------------- 3x3 conv: m-tile 64, n-tile 256, all-9-tap weight stage ----------------
// mode 0: out16[b][n][256] = acc + corr[m][n]
// mode 1: out32[b][m][4096] = (acc + bias[m])*x + x
__global__ __launch_bounds__(256) void conv3x3_mfma(
    const u16* __restrict__ inT, const u16* __restrict__ wr,
    const float* __restrict__ cb, const float* __restrict__ xres,
    u16* __restrict__ out16, float* __restrict__ out32, int mode)
{
  __shared__ __align__(16) u16 Ws[64 * 288];   // 36.9 KB: 64 m x 9 taps x 32 ch
  __shared__ __align__(16) u16 Hs[396 * 32];   // 25.3 KB: 6 rows x 66 cols x 32 ch
  int b = blockIdx.z;
  int m0 = blockIdx.y * 64;
  int n0 = blockIdx.x * 256;
  int r0 = n0 >> 6;                             // tile covers image rows r0..r0+3
  int t = threadIdx.x, wave = t >> 6, lane = t & 63;
  int wi = (wave >> 1) * 32, wj = (wave & 1) * 128;
  int li = lane & 15, quad = lane >> 4;
  const u16* inb = inT + (long)b * NB;
  f32x4 acc[2][8];
#pragma unroll
  for (int i = 0; i < 2; i++)
#pragma unroll
    for (int j = 0; j < 8; j++) acc[i][j] = (f32x4){0.f, 0.f, 0.f, 0.f};

#pragma unroll 1
  for (int c0 = 0; c0 < 256; c0 += 32) {
    // Ws: 2304 chunks of 16B, 9 rounds
#pragma unroll
    for (int i = 0; i < 9; i++) {
      int chunk = i * 256 + t;
      int m = chunk / 36, rr = chunk - m * 36;
      int tap = rr >> 2, q = rr & 3;
      ASYNC16(wr + (long)(m0 + m) * 2304 + tap * 256 + c0 + q * 8,
              &Ws[(i * 256 + wave * 64) * 8]);
    }
    // Hs: 1584 chunks, 7 rounds (last partial); OOB chunks zeroed via LDS store
#pragma unroll
    for (int i = 0; i < 7; i++) {
      int chunk = i * 256 + t;
      if (chunk < 1584) {
        int pos = chunk >> 2, q = chunk & 3;
        int rr = pos / 66, xx = pos - rr * 66;
        int ri = r0 + rr - 1, xi = xx - 1;
        if ((unsigned)ri < 64u && (unsigned)xi < 64u) {
          ASYNC16(inb + (long)((ri << 6) + xi) * 256 + c0 + q * 8,
                  &Hs[(i * 256 + wave * 64) * 8]);
        } else {
          float4 z = {0.f, 0.f, 0.f, 0.f};
          *(float4*)&Hs[chunk * 8] = z;
        }
      }
    }
    __syncthreads();
#pragma unroll
    for (int d = 0; d < 9; d++) {
      int dy = d / 3, dx = d - dy * 3;
      short8 af[2], bf[8];
#pragma unroll
      for (int s = 0; s < 2; s++)
        af[s] = *(const short8*)&Ws[(wi + s * 16 + li) * 288 + d * 32 + quad * 8];
#pragma unroll
      for (int s = 0; s < 8; s++) {
        int pl = wj + s * 16 + li;
        int hp = ((pl >> 6) + dy) * 66 + (pl & 63) + dx;
        bf[s] = *(const short8*)&Hs[hp * 32 + quad * 8];
      }
#pragma unroll
      for (int si = 0; si < 2; si++)
#pragma unroll
        for (int sj = 0; sj < 8; sj++)
          acc[si][sj] = __builtin_amdgcn_mfma_f32_16x16x32_bf16(af[si], bf[sj], acc[si][sj], 0, 0, 0);
    }
    __syncthreads();
  }

#pragma unroll
  for (int si = 0; si < 2; si++)
#pragma unroll
    for (int sj = 0; sj < 8; sj++) {
      int n = n0 + wj + sj * 16 + li;
#pragma unroll
      for (int r = 0; r < 4; r++) {
        int m = m0 + wi + si * 16 + quad * 4 + r;
        float v = acc[si][sj][r];
        if (mode == 0) {
          v += cb[m * 4096 + n];                       // corr field (incl. c1b + rb term)
          out16[(long)b * NB + (long)n * 256 + m] = f2b(v);
        } else {
          v += cb[m];
          long a = (long)b * NB + (long)m * 4096 + n;
          float xv = xres[a];
          out32[a] = fmaf(v, xv, xv);
        }
      }
    }
}

// ---------------- host ----------------
extern "C" void kernel_launch(void* const* d_in, const int* in_sizes, int n_in,
                              void* d_out, int out_size, void* d_ws, size_t ws_size,
                              hipStream_t stream)
{
  const float* x   = (const float*)d_in[0];
  const float* qw  = (const float*)d_in[1];
  const float* qb  = (const float*)d_in[2];
  const float* kw  = (const float*)d_in[3];
  const float* kb  = (const float*)d_in[4];
  const float* vw  = (const float*)d_in[5];
  const float* vb  = (const float*)d_in[6];
  const float* rw  = (const float*)d_in[7];
  const float* rb  = (const float*)d_in[8];
  const float* c1w = (const float*)d_in[9];
  const float* c1b = (const float*)d_in[10];
  const float* c2w = (const float*)d_in[11];
  const float* c2b = (const float*)d_in[12];

  // ws layout (u16 units)
  u16* U     = (u16*)d_ws;
  u16* xT16  = U;                     // 8388608 ; later wvT16
  u16* Qt16  = U + 8388608;           // 8388608 ; later h1T16
  u16* KV16  = U + 16777216;          // 16777216 (K rows 0-255, V rows 256-511 per b)
  u16* wr2   = U + 33554432;          // 589824
  u16* kvT16 = U + 34144256;          // 524288
  float* Fws = (float*)(U + 34668544);
  float* ksum = Fws;                  // 2048
  float* vsum = Fws + 2048;           // 2048

  // d_out scratch (all dead before conv2 writes d_out; conv2 reads NOTHING here)
  char* ob = (char*)d_out;
  float* kvpart = (float*)(ob + 0);           // 16777216 B
  float* den    = (float*)(ob + 16777216);    // 131072
  float* rsqK   = (float*)(ob + 16908288);    // 131072
  float* corr   = (float*)(ob + 17039360);    // 4194304
  u16*   w1p16  = (u16*)(ob + 21233664);      // 1179648
  u16*   wr1    = (u16*)(ob + 22413312);      // 1179648
  float* T      = (float*)(ob + 23592960);    // 36864
  u16*   rwT16  = (u16*)(ob + 23629824);      // 131072
  u16*   qw16   = (u16*)(ob + 23760896);      // 131072
  u16*   kvw16  = (u16*)(ob + 23891968);      // 262144
  float* kvbias = (float*)(ob + 24154112);    // 2048
  float* outF   = (float*)d_out;

  u16* wvT16 = xT16;
  u16* h1T16 = Qt16;

  dim3 blk(256);

  prep1<<<5633, blk, 0, stream>>>(qw, kw, vw, rw, c1w, c2w, kb, vb,
                                  qw16, kvw16, rwT16, wr1, wr2, kvbias);
  prep_T<<<9, blk, 0, stream>>>(c1w, rb, T);
  corr_k<<<4096, blk, 0, stream>>>(T, c1b, corr);
  transposeX<<<dim3(64, 4, 8), blk, 0, stream>>>(x, xT16);

  // w1' = wr1 @ rwT : folds rw into conv1 weights
  gemm_nt<<<dim3(2, 18, 1), blk, 0, stream>>>(wr1, rwT16, w1p16,
      256, 256, 256, 0L, 0L, 0L, 256L, 1L, 0, nullptr, nullptr);
  // Qt[b][n][ck] = xT @ qw^T + qb
  gemm_nt<<<dim3(2, 32, 8), blk, 0, stream>>>(xT16, qw16, Qt16,
      256, 256, 256, NB, 0L, NB, 256L, 1L, 0, nullptr, qb);
  // KV[b][cq][n] = [kw|vw] @ x + [kb|vb]
  gemm_nt<<<dim3(32, 4, 8), blk, 0, stream>>>(kvw16, xT16, KV16,
      256, 256, 256, 0L, NB, 2 * NB, 4096L, 1L, 0, kvbias, nullptr);

  normQ<<<8192, blk, 0, stream>>>(Qt16);
  sumsqK<<<256, blk, 0, stream>>>(KV16, rsqK);
  scale_sums<<<4096, blk, 0, stream>>>(KV16, rsqK, ksum, vsum);
  denom_k<<<8192, blk, 0, stream>>>(Qt16, ksum, den);

  gemm_kv<<<dim3(2, 2, 64), blk, 0, stream>>>(KV16, kvpart);
  reduce_kv<<<2048, blk, 0, stream>>>(kvpart, kvT16);

  // wvT[b][n][cv] = (Qt @ kv + vsum)*den   (coalesced stores)
  gemm_nt<<<dim3(2, 32, 8), blk, 0, stream>>>(Qt16, kvT16, wvT16,
      256, 256, 256, NB, 65536L, NB, 256L, 1L, 2, vsum, den);

  conv3x3_mfma<<<dim3(16, 4, 8), blk, 0, stream>>>(wvT16, w1p16, corr, nullptr,
                                                   h1T16, nullptr, 0);
  conv3x3_mfma<<<dim3(16, 4, 8), blk, 0, stream>>>(h1T16, wr2, c2b, x,
                                                   nullptr, outF, 1);
}